// Round 14
// baseline (249.359 us; speedup 1.0000x reference)
//
#include <hip/hip_runtime.h>
#include <hip/hip_bf16.h>

#define NN 50000
#define EE 800000
#define CC 64
#define HH 2
#define LL 3
#define CAP 64     // slots per node (Poisson(16): P(>=64) ~ 1e-13)
#define NB 782     // dst buckets of 64 nodes: (50000+63)/64
#define BCAP 1280  // per-bucket capacity (mean 1023, +8 sigma)
#define CHUNK 8192 // edges per k_bin block
#define NBLK ((EE + CHUNK - 1) / CHUNK)   // 98

// ---------------- build ----------------

// Block-local counting sort: LDS stash + LDS histogram, ONE global atomic per
// (block,bucket), then place at base+rank (merged writeback).
__global__ __launch_bounds__(1024) void k_bin(const int* __restrict__ ei,
                                              int* __restrict__ bcnt,
                                              unsigned int* __restrict__ bucket) {
    __shared__ unsigned int stash[CHUNK];
    __shared__ int hist[NB];
    __shared__ int rank[NB];
    __shared__ int base[NB];

    int c0 = blockIdx.x * CHUNK;
    int n = EE - c0; if (n > CHUNK) n = CHUNK;

    for (int b = threadIdx.x; b < NB; b += 1024) { hist[b] = 0; rank[b] = 0; }
    __syncthreads();

    for (int k = threadIdx.x; k < n; k += 1024) {
        unsigned int s = (unsigned int)ei[c0 + k];
        unsigned int d = (unsigned int)ei[EE + c0 + k];
        stash[k] = (d << 16) | s;
        atomicAdd(&hist[d >> 6], 1);
    }
    __syncthreads();

    for (int b = threadIdx.x; b < NB; b += 1024) {
        int c = hist[b];
        base[b] = c ? atomicAdd(&bcnt[b], c) : 0;
    }
    __syncthreads();

    for (int k = threadIdx.x; k < n; k += 1024) {
        unsigned int pk = stash[k];
        int b = (int)(pk >> 22);
        int r = atomicAdd(&rank[b], 1);
        int pos = base[b] + r;
        if (pos < BCAP) bucket[(size_t)b * BCAP + pos] = pk;
    }
}

// one block per bucket; bucket b exclusively owns dsts [64b,64b+64) -> LDS
// rank counters (no global atomics); cnt written coalesced.
__global__ __launch_bounds__(256) void k_place(const unsigned int* __restrict__ bucket,
                                               const int* __restrict__ bcnt,
                                               int* __restrict__ cnt,
                                               unsigned short* __restrict__ slots) {
    __shared__ int lcnt[64];
    int b = blockIdx.x;
    if (threadIdx.x < 64) lcnt[threadIdx.x] = 0;
    __syncthreads();
    int node0 = b << 6;
    int m = bcnt[b];
    if (m > BCAP) m = BCAP;
    const unsigned int* src = bucket + (size_t)b * BCAP;
    for (int i = threadIdx.x; i < m; i += 256) {
        unsigned int pk = src[i];
        int d = (int)(pk >> 16);
        int s = (int)(pk & 0xFFFFu);
        int pos = atomicAdd(&lcnt[d - node0], 1);
        if (pos < CAP) slots[(size_t)d * CAP + pos] = (unsigned short)s;
    }
    __syncthreads();
    if (threadIdx.x < 64) {
        int node = node0 + threadIdx.x;
        if (node < NN) cnt[node] = lcnt[threadIdx.x];
    }
}

// x (f32) -> bf16 rows (RNE), packed 2/uint
__global__ void k_cvt(const float* __restrict__ x, unsigned int* __restrict__ hX, int npk) {
    int i = blockIdx.x * blockDim.x + threadIdx.x;
    if (i >= npk) return;
    float2 v = ((const float2*)x)[i];
    unsigned ua = __float_as_uint(v.x);
    unsigned ub = __float_as_uint(v.y);
    ua += 0x7fff + ((ua >> 16) & 1);
    ub += 0x7fff + ((ub >> 16) & 1);
    hX[i] = (ua >> 16) | (ub & 0xffff0000u);
}

// ---------------- fused GAT layer, (cb,e8) layout ----------------
// wave per node; lane = cb*8+e8: e8 = edge slot (8 edges/group), cb = 8-channel
// block (16B bf16 gather per lane). Dot reduce = 3 xor steps over cb; weight
// stays in-lane for the A accumulate (no per-edge broadcast). Self-loop is
// group-0 slot -1 (gathers own row — no special path). No-max softmax.

#define LEAKY(v) fmaxf((v), 0.2f * (v))

__device__ __forceinline__ void unpk8(uint4 u, float* v) {
    v[0] = __uint_as_float(u.x << 16); v[1] = __uint_as_float(u.x & 0xffff0000u);
    v[2] = __uint_as_float(u.y << 16); v[3] = __uint_as_float(u.y & 0xffff0000u);
    v[4] = __uint_as_float(u.z << 16); v[5] = __uint_as_float(u.z & 0xffff0000u);
    v[6] = __uint_as_float(u.w << 16); v[7] = __uint_as_float(u.w & 0xffff0000u);
}

__device__ __forceinline__ unsigned pk2(float a, float b) {
    unsigned ua = __float_as_uint(a);
    unsigned ub = __float_as_uint(b);
    ua += 0x7fff + ((ua >> 16) & 1);
    ub += 0x7fff + ((ub >> 16) & 1);
    return (ua >> 16) | (ub & 0xffff0000u);
}

template <bool FIRST>
__global__ __launch_bounds__(256) void k_gat(const unsigned short* __restrict__ h,
                                             const int* __restrict__ cnt,
                                             const unsigned short* __restrict__ slots,
                                             const float* __restrict__ att_l,
                                             const float* __restrict__ bias_l,
                                             unsigned short* __restrict__ h_out,
                                             float* __restrict__ acc, int n) {
    int wid = threadIdx.x >> 6;
    int lane = threadIdx.x & 63;
    int node = blockIdx.x * 4 + wid;
    if (node >= n) return;
    int e8 = lane & 7;
    int cb = lane >> 3;
    unsigned qb = (unsigned)cb << 4;             // byte offset of 8-bf16 block
    const char* hb = (const char*)h;

    // att: 8 channels per head, f32
    float a0[8], a1[8];
    {
        const float4* p = (const float4*)(att_l + cb * 8);
        float4 t0 = p[0], t1 = p[1];
        a0[0]=t0.x; a0[1]=t0.y; a0[2]=t0.z; a0[3]=t0.w;
        a0[4]=t1.x; a0[5]=t1.y; a0[6]=t1.z; a0[7]=t1.w;
        const float4* p2 = (const float4*)(att_l + CC + cb * 8);
        float4 u0 = p2[0], u1 = p2[1];
        a1[0]=u0.x; a1[1]=u0.y; a1[2]=u0.z; a1[3]=u0.w;
        a1[4]=u1.x; a1[5]=u1.y; a1[6]=u1.z; a1[7]=u1.w;
    }
    float hd[8];
    unpk8(*(const uint4*)(hb + (((unsigned)node << 7) + qb)), hd);
    int deg = cnt[node];
    if (deg > CAP) deg = CAP;
    const unsigned short* row = slots + (size_t)node * CAP;

    float s0 = 0.f, s1 = 0.f;
    float A0[8], A1[8];
#pragma unroll
    for (int j = 0; j < 8; j++) { A0[j] = 0.f; A1[j] = 0.f; }

    int ngroups = (deg + 8) >> 3;   // deg real edges + 1 self-loop, groups of 8
    for (int g = 0; g < ngroups; g++) {
        int slot = (g << 3) + e8 - 1;
        bool valid = slot < deg;                 // slot==-1 (self) is valid
        int src = (slot >= 0 && valid) ? (int)row[slot] : node;
        float v[8];
        unpk8(*(const uint4*)(hb + (((unsigned)src << 7) + qb)), v);
        float p0 = 0.f, p1 = 0.f;
#pragma unroll
        for (int j = 0; j < 8; j++) {
            float t = LEAKY(v[j] + hd[j]);
            p0 = fmaf(t, a0[j], p0);
            p1 = fmaf(t, a1[j], p1);
        }
        // reduce dot over the 8 channel blocks (lane bits 3,4,5)
        p0 += __shfl_xor(p0, 8); p0 += __shfl_xor(p0, 16); p0 += __shfl_xor(p0, 32);
        p1 += __shfl_xor(p1, 8); p1 += __shfl_xor(p1, 16); p1 += __shfl_xor(p1, 32);
        float w0 = valid ? __expf(p0) : 0.f;
        float w1 = valid ? __expf(p1) : 0.f;
        s0 += w0; s1 += w1;
#pragma unroll
        for (int j = 0; j < 8; j++) {
            A0[j] = fmaf(w0, v[j], A0[j]);
            A1[j] = fmaf(w1, v[j], A1[j]);
        }
    }

    // totals over the 8 edge-slots (lane bits 0,1,2)
    s0 += __shfl_xor(s0, 1); s0 += __shfl_xor(s0, 2); s0 += __shfl_xor(s0, 4);
    s1 += __shfl_xor(s1, 1); s1 += __shfl_xor(s1, 2); s1 += __shfl_xor(s1, 4);
    float inv0 = 0.5f / (s0 + 1e-16f);           // fold mean-over-heads
    float inv1 = 0.5f / (s1 + 1e-16f);
    float o[8];
#pragma unroll
    for (int j = 0; j < 8; j++) o[j] = A0[j] * inv0 + A1[j] * inv1;
#pragma unroll
    for (int j = 0; j < 8; j++) {
        o[j] += __shfl_xor(o[j], 1);
        o[j] += __shfl_xor(o[j], 2);
        o[j] += __shfl_xor(o[j], 4);
    }

    if (e8 == 0) {                               // 8 lanes, one per channel block
        const float4* bp = (const float4*)(bias_l + cb * 8);
        float4 b0 = bp[0], b1 = bp[1];
        o[0] += b0.x; o[1] += b0.y; o[2] += b0.z; o[3] += b0.w;
        o[4] += b1.x; o[5] += b1.y; o[6] += b1.z; o[7] += b1.w;
        uint4 opk;
        opk.x = pk2(o[0], o[1]); opk.y = pk2(o[2], o[3]);
        opk.z = pk2(o[4], o[5]); opk.w = pk2(o[6], o[7]);
        *(uint4*)((char*)h_out + (((unsigned)node << 7) + qb)) = opk;
        float4* accp = (float4*)(acc + (size_t)node * CC + cb * 8);
        float4 c0, c1;
        if (FIRST) {
            c0.x = 0.25f * (hd[0] + o[0]); c0.y = 0.25f * (hd[1] + o[1]);
            c0.z = 0.25f * (hd[2] + o[2]); c0.w = 0.25f * (hd[3] + o[3]);
            c1.x = 0.25f * (hd[4] + o[4]); c1.y = 0.25f * (hd[5] + o[5]);
            c1.z = 0.25f * (hd[6] + o[6]); c1.w = 0.25f * (hd[7] + o[7]);
        } else {
            c0 = accp[0]; c1 = accp[1];
            c0.x += 0.25f * o[0]; c0.y += 0.25f * o[1];
            c0.z += 0.25f * o[2]; c0.w += 0.25f * o[3];
            c1.x += 0.25f * o[4]; c1.y += 0.25f * o[5];
            c1.z += 0.25f * o[6]; c1.w += 0.25f * o[7];
        }
        accp[0] = c0; accp[1] = c1;
    }
}

// ---------------- launch ----------------

static inline size_t align256(size_t x) { return (x + 255) & ~(size_t)255; }

extern "C" void kernel_launch(void* const* d_in, const int* in_sizes, int n_in,
                              void* d_out, int out_size, void* d_ws, size_t ws_size,
                              hipStream_t stream) {
    const float* x    = (const float*)d_in[0];
    const int*   ei   = (const int*)d_in[1];
    const float* att  = (const float*)d_in[2];
    const float* bias = (const float*)d_in[3];
    float* acc = (float*)d_out;   // fp32 output; feats-mean accumulated here

    char* w = (char*)d_ws;
    int* bcnt   = (int*)w;              w += align256((size_t)NB * sizeof(int));
    int* cnt    = (int*)w;              w += align256((size_t)NN * sizeof(int));
    unsigned int* bucket = (unsigned int*)w;
    w += align256((size_t)NB * BCAP * sizeof(unsigned int));
    unsigned short* slots = (unsigned short*)w;
    w += align256((size_t)NN * CAP * sizeof(unsigned short));
    unsigned short* hX = (unsigned short*)w;  w += align256((size_t)NN * CC * 2);
    unsigned short* hA = (unsigned short*)w;  w += align256((size_t)NN * CC * 2);
    unsigned short* hB = (unsigned short*)w;  w += align256((size_t)NN * CC * 2);

    const int B = 256;

    // build (per call; ws is re-poisoned before every launch)
    hipMemsetAsync(bcnt, 0, (size_t)NB * sizeof(int), stream);
    k_bin<<<NBLK, 1024, 0, stream>>>(ei, bcnt, bucket);
    k_place<<<NB, B, 0, stream>>>(bucket, bcnt, cnt, slots);
    int npk = NN * CC / 2;
    k_cvt<<<(npk + B - 1) / B, B, 0, stream>>>(x, (unsigned int*)hX, npk);

    // 3 fused GAT layers (bf16 h); layer 0 seeds acc = 0.25*(x + h1)
    k_gat<true><<<(NN + 3) / 4, B, 0, stream>>>(
        hX, cnt, slots, att, bias, hA, acc, NN);
    k_gat<false><<<(NN + 3) / 4, B, 0, stream>>>(
        hA, cnt, slots, att + (size_t)HH * CC, bias + CC, hB, acc, NN);
    k_gat<false><<<(NN + 3) / 4, B, 0, stream>>>(
        hB, cnt, slots, att + (size_t)2 * HH * CC, bias + 2 * CC, hA, acc, NN);
}

// Round 15
// 217.574 us; speedup vs baseline: 1.1461x; 1.1461x over previous
//
#include <hip/hip_runtime.h>
#include <hip/hip_bf16.h>

#define NN 50000
#define EE 800000
#define CC 64
#define HH 2
#define LL 3
#define CAP 64     // slots per node (Poisson(16): P(>=64) ~ 1e-13)
#define NB 782     // dst buckets of 64 nodes: (50000+63)/64
#define BCAP 1280  // per-bucket capacity (mean 1023, +8 sigma)
#define CHUNK 8192 // edges per k_bin block
#define NBLK ((EE + CHUNK - 1) / CHUNK)   // 98

// ---------------- build ----------------

// Block-local counting sort: LDS stash + LDS histogram, ONE global atomic per
// (block,bucket) (77k vs 800k — device atomics serialize at the fabric),
// then place at base+rank (merged writeback).
__global__ __launch_bounds__(1024) void k_bin(const int* __restrict__ ei,
                                              int* __restrict__ bcnt,
                                              unsigned int* __restrict__ bucket) {
    __shared__ unsigned int stash[CHUNK];
    __shared__ int hist[NB];
    __shared__ int rank[NB];
    __shared__ int base[NB];

    int c0 = blockIdx.x * CHUNK;
    int n = EE - c0; if (n > CHUNK) n = CHUNK;

    for (int b = threadIdx.x; b < NB; b += 1024) { hist[b] = 0; rank[b] = 0; }
    __syncthreads();

    for (int k = threadIdx.x; k < n; k += 1024) {
        unsigned int s = (unsigned int)ei[c0 + k];
        unsigned int d = (unsigned int)ei[EE + c0 + k];
        stash[k] = (d << 16) | s;
        atomicAdd(&hist[d >> 6], 1);
    }
    __syncthreads();

    for (int b = threadIdx.x; b < NB; b += 1024) {
        int c = hist[b];
        base[b] = c ? atomicAdd(&bcnt[b], c) : 0;
    }
    __syncthreads();

    for (int k = threadIdx.x; k < n; k += 1024) {
        unsigned int pk = stash[k];
        int b = (int)(pk >> 22);
        int r = atomicAdd(&rank[b], 1);
        int pos = base[b] + r;
        if (pos < BCAP) bucket[(size_t)b * BCAP + pos] = pk;
    }
}

// one block per bucket; bucket b exclusively owns dsts [64b,64b+64) -> LDS
// rank counters (no global atomics); cnt written coalesced.
__global__ __launch_bounds__(256) void k_place(const unsigned int* __restrict__ bucket,
                                               const int* __restrict__ bcnt,
                                               int* __restrict__ cnt,
                                               unsigned short* __restrict__ slots) {
    __shared__ int lcnt[64];
    int b = blockIdx.x;
    if (threadIdx.x < 64) lcnt[threadIdx.x] = 0;
    __syncthreads();
    int node0 = b << 6;
    int m = bcnt[b];
    if (m > BCAP) m = BCAP;
    const unsigned int* src = bucket + (size_t)b * BCAP;
    for (int i = threadIdx.x; i < m; i += 256) {
        unsigned int pk = src[i];
        int d = (int)(pk >> 16);
        int s = (int)(pk & 0xFFFFu);
        int pos = atomicAdd(&lcnt[d - node0], 1);
        if (pos < CAP) slots[(size_t)d * CAP + pos] = (unsigned short)s;
    }
    __syncthreads();
    if (threadIdx.x < 64) {
        int node = node0 + threadIdx.x;
        if (node < NN) cnt[node] = lcnt[threadIdx.x];
    }
}

// ---------------- fused GAT layer (R12 — measured best: 48.7us/layer) ----------------
// wave per node; 4 subgroups x 16 lanes; lane holds channel quad q.
// (1) adjacent-pair edges -> one u32 index load per 2 edges; (2) 32-bit byte
// offsets -> SGPR-base+voffset loads; (3) branchless 1/4-weight self-loop.
// No-max softmax (alpha provably bounded, exp safe). 2-deep gather pipeline
// (4-deep regressed R6/R8; (cb,e8) relayout regressed R14 via coalescing loss).

#define LEAKY(v) fmaxf((v), 0.2f * (v))

template <bool FIRST>
__global__ __launch_bounds__(256) void k_gat(const float* __restrict__ h,
                                             const int* __restrict__ cnt,
                                             const unsigned short* __restrict__ slots,
                                             const float* __restrict__ att_l,
                                             const float* __restrict__ bias_l,
                                             float* __restrict__ h_out,
                                             float* __restrict__ acc, int n) {
    int wid = threadIdx.x >> 6;
    int lane = threadIdx.x & 63;
    int node = blockIdx.x * 4 + wid;
    if (node >= n) return;
    int sub = lane >> 4, q = lane & 15;
    unsigned qb = (unsigned)q << 4;              // byte offset of quad in a row
    const char* hb = (const char*)h;
    float4 a0q = ((const float4*)att_l)[q];
    float4 a1q = ((const float4*)att_l)[16 + q];
    float4 hd = *(const float4*)(hb + (((unsigned)node << 8) + qb));
    int deg = cnt[node];
    if (deg > CAP) deg = CAP;
    const unsigned* rowu = (const unsigned*)(slots + (size_t)node * CAP);

    float s0, s1;
    float4 A0, A1;

    // self-loop: all 4 subgroups, weight 1/4 (merge restores 1x) — no branch
    {
        float vx = LEAKY(2.f * hd.x), vy = LEAKY(2.f * hd.y);
        float vz = LEAKY(2.f * hd.z), vw = LEAKY(2.f * hd.w);
        float p0 = vx * a0q.x + vy * a0q.y + vz * a0q.z + vw * a0q.w;
        float p1 = vx * a1q.x + vy * a1q.y + vz * a1q.z + vw * a1q.w;
#pragma unroll
        for (int m = 8; m; m >>= 1) {
            p0 += __shfl_xor(p0, m);
            p1 += __shfl_xor(p1, m);
        }
        float e0 = 0.25f * __expf(p0), e1 = 0.25f * __expf(p1);
        s0 = e0; s1 = e1;
        A0.x = e0 * hd.x; A0.y = e0 * hd.y; A0.z = e0 * hd.z; A0.w = e0 * hd.w;
        A1.x = e1 * hd.x; A1.y = e1 * hd.y; A1.z = e1 * hd.z; A1.w = e1 * hd.w;
    }

    // main loop: subgroup takes edge pairs (2p, 2p+1) — one u32 = both indices
    int npair = deg >> 1;
    for (int p = sub; p < npair; p += 4) {
        unsigned pk = rowu[p];
        float4 va = *(const float4*)(hb + (((pk & 0xFFFFu) << 8) + qb));
        float4 vb = *(const float4*)(hb + (((pk >> 16) << 8) + qb));
        float vx, vy, vz, vw;
        vx = LEAKY(va.x + hd.x); vy = LEAKY(va.y + hd.y);
        vz = LEAKY(va.z + hd.z); vw = LEAKY(va.w + hd.w);
        float pa0 = vx * a0q.x + vy * a0q.y + vz * a0q.z + vw * a0q.w;
        float pa1 = vx * a1q.x + vy * a1q.y + vz * a1q.z + vw * a1q.w;
        vx = LEAKY(vb.x + hd.x); vy = LEAKY(vb.y + hd.y);
        vz = LEAKY(vb.z + hd.z); vw = LEAKY(vb.w + hd.w);
        float pb0 = vx * a0q.x + vy * a0q.y + vz * a0q.z + vw * a0q.w;
        float pb1 = vx * a1q.x + vy * a1q.y + vz * a1q.z + vw * a1q.w;
#pragma unroll
        for (int m = 8; m; m >>= 1) {
            pa0 += __shfl_xor(pa0, m); pa1 += __shfl_xor(pa1, m);
            pb0 += __shfl_xor(pb0, m); pb1 += __shfl_xor(pb1, m);
        }
        float ea0 = __expf(pa0), ea1 = __expf(pa1);
        float eb0 = __expf(pb0), eb1 = __expf(pb1);
        s0 += ea0 + eb0;
        s1 += ea1 + eb1;
        A0.x += ea0 * va.x + eb0 * vb.x; A0.y += ea0 * va.y + eb0 * vb.y;
        A0.z += ea0 * va.z + eb0 * vb.z; A0.w += ea0 * va.w + eb0 * vb.w;
        A1.x += ea1 * va.x + eb1 * vb.x; A1.y += ea1 * va.y + eb1 * vb.y;
        A1.z += ea1 * va.z + eb1 * vb.z; A1.w += ea1 * va.w + eb1 * vb.w;
    }

    // tail: one odd edge, handled by one subgroup (uniform per subgroup)
    if (deg & 1) {
        int t = deg - 1;
        if (sub == ((t >> 1) & 3)) {
            unsigned s = ((const unsigned short*)rowu)[t];
            float4 hv = *(const float4*)(hb + ((s << 8) + qb));
            float vx = LEAKY(hv.x + hd.x), vy = LEAKY(hv.y + hd.y);
            float vz = LEAKY(hv.z + hd.z), vw = LEAKY(hv.w + hd.w);
            float p0 = vx * a0q.x + vy * a0q.y + vz * a0q.z + vw * a0q.w;
            float p1 = vx * a1q.x + vy * a1q.y + vz * a1q.z + vw * a1q.w;
#pragma unroll
            for (int m = 8; m; m >>= 1) {
                p0 += __shfl_xor(p0, m);
                p1 += __shfl_xor(p1, m);
            }
            float e0 = __expf(p0), e1 = __expf(p1);
            s0 += e0; s1 += e1;
            A0.x += e0 * hv.x; A0.y += e0 * hv.y; A0.z += e0 * hv.z; A0.w += e0 * hv.w;
            A1.x += e1 * hv.x; A1.y += e1 * hv.y; A1.z += e1 * hv.z; A1.w += e1 * hv.w;
        }
    }

    // merge the 4 subgroups: plain sums
#pragma unroll
    for (int step = 16; step <= 32; step <<= 1) {
        s0 += __shfl_xor(s0, step);
        s1 += __shfl_xor(s1, step);
        A0.x += __shfl_xor(A0.x, step); A0.y += __shfl_xor(A0.y, step);
        A0.z += __shfl_xor(A0.z, step); A0.w += __shfl_xor(A0.w, step);
        A1.x += __shfl_xor(A1.x, step); A1.y += __shfl_xor(A1.y, step);
        A1.z += __shfl_xor(A1.z, step); A1.w += __shfl_xor(A1.w, step);
    }

    if (sub == 0) {
        float inv0 = 0.5f / (s0 + 1e-16f);       // fold mean-over-heads
        float inv1 = 0.5f / (s1 + 1e-16f);
        float4 b4 = ((const float4*)bias_l)[q];
        float4 o;
        o.x = A0.x * inv0 + A1.x * inv1 + b4.x;
        o.y = A0.y * inv0 + A1.y * inv1 + b4.y;
        o.z = A0.z * inv0 + A1.z * inv1 + b4.z;
        o.w = A0.w * inv0 + A1.w * inv1 + b4.w;
        ((float4*)h_out)[(size_t)node * 16 + q] = o;
        float4* accp = (float4*)acc + (size_t)node * 16 + q;
        float4 ac;
        if (FIRST) {
            // acc = 0.25*(x + h1); hd holds x's row quad
            ac.x = 0.25f * (hd.x + o.x); ac.y = 0.25f * (hd.y + o.y);
            ac.z = 0.25f * (hd.z + o.z); ac.w = 0.25f * (hd.w + o.w);
        } else {
            ac = *accp;
            ac.x += 0.25f * o.x; ac.y += 0.25f * o.y;
            ac.z += 0.25f * o.z; ac.w += 0.25f * o.w;
        }
        *accp = ac;
    }
}

// ---------------- launch ----------------

static inline size_t align256(size_t x) { return (x + 255) & ~(size_t)255; }

extern "C" void kernel_launch(void* const* d_in, const int* in_sizes, int n_in,
                              void* d_out, int out_size, void* d_ws, size_t ws_size,
                              hipStream_t stream) {
    const float* x    = (const float*)d_in[0];
    const int*   ei   = (const int*)d_in[1];
    const float* att  = (const float*)d_in[2];
    const float* bias = (const float*)d_in[3];
    float* acc = (float*)d_out;   // fp32 output; feats-mean accumulated here

    char* w = (char*)d_ws;
    int* bcnt   = (int*)w;              w += align256((size_t)NB * sizeof(int));
    int* cnt    = (int*)w;              w += align256((size_t)NN * sizeof(int));
    unsigned int* bucket = (unsigned int*)w;
    w += align256((size_t)NB * BCAP * sizeof(unsigned int));
    unsigned short* slots = (unsigned short*)w;
    w += align256((size_t)NN * CAP * sizeof(unsigned short));
    float* hA   = (float*)w;            w += align256((size_t)NN * CC * sizeof(float));
    float* hB   = (float*)w;            w += align256((size_t)NN * CC * sizeof(float));

    const int B = 256;

    // build (per call; ws is re-poisoned before every launch)
    hipMemsetAsync(bcnt, 0, (size_t)NB * sizeof(int), stream);
    k_bin<<<NBLK, 1024, 0, stream>>>(ei, bcnt, bucket);
    k_place<<<NB, B, 0, stream>>>(bucket, bcnt, cnt, slots);

    // 3 fused GAT layers; layer 0 reads x directly and seeds acc = 0.25*(x + h1)
    k_gat<true><<<(NN + 3) / 4, B, 0, stream>>>(
        x, cnt, slots, att, bias, hA, acc, NN);
    k_gat<false><<<(NN + 3) / 4, B, 0, stream>>>(
        hA, cnt, slots, att + (size_t)HH * CC, bias + CC, hB, acc, NN);
    k_gat<false><<<(NN + 3) / 4, B, 0, stream>>>(
        hB, cnt, slots, att + (size_t)2 * HH * CC, bias + 2 * CC, hA, acc, NN);
}